// Round 18
// baseline (223.806 us; speedup 1.0000x reference)
//
#include <hip/hip_runtime.h>
#include <hip/hip_bf16.h>
#include <stdint.h>

typedef __attribute__((ext_vector_type(8))) short short8;
typedef __attribute__((ext_vector_type(4))) float f32x4;
typedef unsigned int u32;
typedef unsigned short u16;

static constexpr int N_TOK = 1024;
static constexpr int DDIM = 2048;
static constexpr int FDIM = 1408;
static constexpr int NEXP = 8;
static constexpr int MAXROWS = 4096;    // 256-row padding: 2048 + 8*255 < 4096
static constexpr int NT128 = 32;        // max 128-tiles over padded space
static constexpr int NT256 = 16;        // max 256-tiles

// ---- workspace byte offsets ----
static constexpr size_t O_META   = 0;                                  // 64 ints
static constexpr size_t O_TE128  = 256;                                // 32 ints
static constexpr size_t O_TR128  = 384;                                // 32 ints
static constexpr size_t O_TE256  = 512;                                // 32 ints
static constexpr size_t O_TR256  = 640;                                // 32 ints
static constexpr size_t O_ROWTOK = 768;                                // MAXROWS ints
static constexpr size_t O_TOKROWS= O_ROWTOK + (size_t)MAXROWS * 4;     // 2048 ints
static constexpr size_t O_SEL    = O_TOKROWS + 2048 * 4;               // 2048 ints
static constexpr size_t O_W      = O_SEL + 2048 * 4;                   // 2048 floats
static constexpr size_t O_XBF    = (O_W + 2048 * 4 + 255) & ~(size_t)255; // (N_TOK+1)*DDIM bf16
static constexpr size_t O_H      = O_XBF + (size_t)(N_TOK + 1) * DDIM * 2; // MAXROWS*FDIM bf16
static constexpr size_t O_EO     = O_H + (size_t)MAXROWS * FDIM * 2;   // MAXROWS*DDIM bf16

static __device__ __forceinline__ u16 f2bf(float f) {
    return __builtin_bit_cast(u16, __float2bfloat16(f));   // RNE via v_cvt
}
static __device__ __forceinline__ float bf2f(u16 s) {
    u32 u = ((u32)s) << 16;
    return __builtin_bit_cast(float, u);
}
static __device__ __forceinline__ u32 pack2(float a, float b) {
    return (u32)f2bf(a) | ((u32)f2bf(b) << 16);
}
// async global->LDS DMA, 16B/lane. LDS base wave-uniform; HW adds lane*16.
static __device__ __forceinline__ void gload16(const void* g, void* l) {
    __builtin_amdgcn_global_load_lds(
        (const __attribute__((address_space(1))) void*)g,
        (__attribute__((address_space(3))) void*)l, 16, 0, 0);
}
#define PIN() __builtin_amdgcn_sched_barrier(0)
// publish LDS writes + raw barrier (no vmcnt drain — loads stay in flight)
static __device__ __forceinline__ void sync_lgkm() {
    asm volatile("s_waitcnt lgkmcnt(0)" ::: "memory");
    __builtin_amdgcn_s_barrier();
    __builtin_amdgcn_sched_barrier(0);
}

// ------- router (+fused xcast): logits, top-2, softmax; writes xbf ---------
__global__ __launch_bounds__(256) void router_kernel(
    const float* __restrict__ x, const float* __restrict__ gw,
    int* __restrict__ sel, float* __restrict__ wout, u16* __restrict__ xbf)
{
    __shared__ float xs[DDIM];
    __shared__ float lg[NEXP];
    const int tok = blockIdx.x;
    const float* xr = x + (size_t)tok * DDIM;
    for (int i = threadIdx.x; i < DDIM / 4; i += 256)
        ((float4*)xs)[i] = ((const float4*)xr)[i];
    __syncthreads();
    {
        const int i = threadIdx.x * 8;
        uint4 v;
        v.x = pack2(xs[i], xs[i + 1]);     v.y = pack2(xs[i + 2], xs[i + 3]);
        v.z = pack2(xs[i + 4], xs[i + 5]); v.w = pack2(xs[i + 6], xs[i + 7]);
        *(uint4*)(xbf + (size_t)tok * DDIM + i) = v;
        if (tok == 0)                      // zero pad row (gathers of tok==-1)
            *(uint4*)(xbf + (size_t)N_TOK * DDIM + i) = uint4{0u, 0u, 0u, 0u};
    }
    const int wid = threadIdx.x >> 6, lane = threadIdx.x & 63;
    for (int i = 0; i < 2; i++) {
        const int e = wid * 2 + i;
        const float* g = gw + (size_t)e * DDIM;
        float s = 0.f;
        for (int k = lane; k < DDIM; k += 64) s += xs[k] * g[k];
        for (int off = 32; off > 0; off >>= 1) s += __shfl_down(s, off);
        if (lane == 0) lg[e] = s;
    }
    __syncthreads();
    if (threadIdx.x == 0) {
        int i1 = 0;
        for (int e = 1; e < NEXP; e++) if (lg[e] > lg[i1]) i1 = e;
        int i2 = -1;
        for (int e = 0; e < NEXP; e++) {
            if (e == i1) continue;
            if (i2 < 0 || lg[e] > lg[i2]) i2 = e;
        }
        const float e2 = __expf(lg[i2] - lg[i1]);
        const float w1 = 1.f / (1.f + e2);
        sel[tok * 2] = i1; sel[tok * 2 + 1] = i2;
        wout[tok * 2] = w1; wout[tok * 2 + 1] = e2 * w1;
    }
}

// ---- routing build: 256-padded row space; 128-tile table covers FULL pad ----
__global__ __launch_bounds__(512) void build_kernel(
    const int* __restrict__ sel,
    int* __restrict__ meta, int* __restrict__ te128, int* __restrict__ tr128,
    int* __restrict__ te256, int* __restrict__ tr256,
    int* __restrict__ row_tok, int* __restrict__ tok_rows)
{
    __shared__ int s0[N_TOK], s1[N_TOK];
    __shared__ u16 p0[N_TOK], p1[N_TOK];
    __shared__ int counts[NEXP], offs[NEXP];
    for (int i = threadIdx.x; i < N_TOK; i += 512) {
        s0[i] = sel[i * 2]; s1[i] = sel[i * 2 + 1];
    }
    __syncthreads();
    const int e = threadIdx.x >> 6, lane = threadIdx.x & 63;
    int base = 0;
    for (int c = 0; c < N_TOK / 64; c++) {
        const int tk = c * 64 + lane;
        const int slot = (s0[tk] == e) ? 0 : ((s1[tk] == e) ? 1 : -1);
        const unsigned long long m = __ballot(slot >= 0);
        const int pre = __popcll(m & ((1ull << lane) - 1ull));
        if (slot == 0) p0[tk] = (u16)(base + pre);
        else if (slot == 1) p1[tk] = (u16)(base + pre);
        base += __popcll(m);
    }
    if (lane == 0) counts[e] = base;
    __syncthreads();
    if (threadIdx.x == 0) {
        int off = 0, n128 = 0, n256 = 0;
        for (int qq = 0; qq < NEXP; qq++) {
            offs[qq] = off;
            const int pc = (counts[qq] + 255) & ~255;
            for (int i = 0; i < pc / 128; i++) { te128[n128] = qq; tr128[n128] = off + i * 128; n128++; }
            for (int i = 0; i < pc / 256; i++) { te256[n256] = qq; tr256[n256] = off + i * 256; n256++; }
            off += pc;
        }
        meta[0] = n128; meta[1] = off; meta[2] = n256;
    }
    __syncthreads();
    const int off = offs[e];
    for (int c = 0; c < N_TOK / 64; c++) {
        const int tk = c * 64 + lane;
        const int slot = (s0[tk] == e) ? 0 : ((s1[tk] == e) ? 1 : -1);
        if (slot >= 0) {
            const int row = off + (slot ? p1[tk] : p0[tk]);
            row_tok[row] = tk;
            tok_rows[tk * 2 + slot] = row;
        }
    }
    const int cnt = counts[e];
    const int pc = (cnt + 255) & ~255;
    for (int p = cnt + lane; p < pc; p += 64) row_tok[off + p] = -1;
}

// ------- mlp1: h = silu(x@G^T)*(x@U^T), BM=128, BN=32/mat, BK=128 -----------
// NT=16 phases (half of r11). K-tile split into two 64-col halves; every LDS
// layout/access within a half is byte-identical to the r11-proven pattern.
// LDS 96 KB -> 1 block/CU; counted vmcnt(8); full phase of latency cover.
__global__ __launch_bounds__(512, 2) void mlp1_kernel(
    const u16* __restrict__ xbf,
    const float* __restrict__ gp, const float* __restrict__ upw,
    u16* __restrict__ h,
    const int* __restrict__ meta, const int* __restrict__ te128,
    const int* __restrict__ tr128, const int* __restrict__ row_tok)
{
    const int tile = blockIdx.y;
    const int nb = blockIdx.x;               // gridDim.x = FDIM/32 = 44
    if (tile >= meta[0]) return;
    const int n0 = nb * 32;
    const int e = te128[tile];
    const int r0g = tr128[tile];

    __shared__ __align__(16) u16 As[2][2][128 * 64];   // [buf][half], 16 KB each
    __shared__ __align__(16) u16 Bs0[2][2][32 * 64];   // [buf][half],  4 KB each
    __shared__ __align__(16) u16 Bs1[2][2][32 * 64];

    const int t = threadIdx.x;
    const int wid = t >> 6, lane = t & 63;
    const int lr = lane & 15, lhi = lane >> 4;
    const int wm = wid * 16;                 // wave-private 16 output rows

    // --- A staging (gload_lds): wave w stages rows wm..wm+16, both halves ---
    const u16* asrc[2];                      // per j: rows wm+j*8..+8, half offset added at call
    int aldsoff[2];
    #pragma unroll
    for (int j = 0; j < 2; j++) {
        const int row = wm + j * 8 + (lane >> 3);
        const int gran = (lane & 7) ^ (row & 7);
        const int tok = row_tok[r0g + row];
        asrc[j] = xbf + (size_t)(tok < 0 ? N_TOK : tok) * DDIM + gran * 8;
        aldsoff[j] = (wid * 2 + j) * 512;
    }

    // --- B staging (reg, cvt-on-write): per thread row rb, float4-col c4;
    //     two halves per tile (k-offsets c4*4 and 64+c4*4 within 128-col tile)
    const int rb = t >> 4, c4 = t & 15;
    const float* brow0 = gp  + (size_t)e * FDIM * DDIM + (size_t)(n0 + rb) * DDIM + c4 * 4;
    const float* brow1 = upw + (size_t)e * FDIM * DDIM + (size_t)(n0 + rb) * DDIM + c4 * 4;
    const int sOffB = rb * 64 + (((c4 >> 1) ^ (rb & 7)) * 8) + (c4 & 1) * 4;

    f32x4 acc0[2], acc1[2];
    acc0[0] = acc0[1] = acc1[0] = acc1[1] = f32x4{0.f, 0.f, 0.f, 0.f};
    // B prefetch: set P/Q, each = {gate half0, gate half1, up half0, up half1}
    float4 p0aP, p0bP, p1aP, p1bP;
    float4 p0aQ, p0bQ, p1aQ, p1bQ;

    auto STAGEA = [&](int bsel, int k0) {    // k0 in u16 units (tile*128)
        #pragma unroll
        for (int j = 0; j < 2; j++) {
            gload16(asrc[j] + k0,      &As[bsel][0][aldsoff[j]]);
            gload16(asrc[j] + k0 + 64, &As[bsel][1][aldsoff[j]]);
        }
    };
    auto LOADB_P = [&](int k0) {             // k0 in f32 units (tile*128)
        p0aP = *(const float4*)(brow0 + k0);      p0bP = *(const float4*)(brow0 + k0 + 64);
        p1aP = *(const float4*)(brow1 + k0);      p1bP = *(const float4*)(brow1 + k0 + 64);
    };
    auto LOADB_Q = [&](int k0) {
        p0aQ = *(const float4*)(brow0 + k0);      p0bQ = *(const float4*)(brow0 + k0 + 64);
        p1aQ = *(const float4*)(brow1 + k0);      p1bQ = *(const float4*)(brow1 + k0 + 64);
    };
    auto STOREB_P = [&](int bsel) {
        uint2 v;
        v.x = pack2(p0aP.x, p0aP.y); v.y = pack2(p0aP.z, p0aP.w);
        *(uint2*)(&Bs0[bsel][0][sOffB]) = v;
        v.x = pack2(p0bP.x, p0bP.y); v.y = pack2(p0bP.z, p0bP.w);
        *(uint2*)(&Bs0[bsel][1][sOffB]) = v;
        v.x = pack2(p1aP.x, p1aP.y); v.y = pack2(p1aP.z, p1aP.w);
        *(uint2*)(&Bs1[bsel][0][sOffB]) = v;
        v.x = pack2(p1bP.x, p1bP.y); v.y = pack2(p1bP.z, p1bP.w);
        *(uint2*)(&Bs1[bsel][1][sOffB]) = v;
    };
    auto STOREB_Q = [&](int bsel) {
        uint2 v;
        v.x = pack2(p0aQ.x, p0aQ.y); v.y = pack2(p0aQ.z, p0aQ.w);
        *(uint2*)(&Bs0[bsel][0][sOffB]) = v;
        v.x = pack2(p0bQ.x, p0bQ.y); v.y = pack2(p0bQ.z, p0bQ.w);
        *(uint2*)(&Bs0[bsel][1][sOffB]) = v;
        v.x = pack2(p1aQ.x, p1aQ.y); v.y = pack2(p1aQ.z, p1aQ.w);
        *(uint2*)(&Bs1[bsel][0][sOffB]) = v;
        v.x = pack2(p1bQ.x, p1bQ.y); v.y = pack2(p1bQ.z, p1bQ.w);
        *(uint2*)(&Bs1[bsel][1][sOffB]) = v;
    };
    auto COMPUTE = [&](int bsel) {
        __builtin_amdgcn_s_setprio(1);
        #pragma unroll
        for (int half = 0; half < 2; half++) {
            #pragma unroll
            for (int ksl = 0; ksl < 2; ksl++) {
                short8 a, b0[2], b1[2];
                {
                    const int rowa = wm + lr;
                    const int gr = (ksl * 4 + lhi) ^ (rowa & 7);
                    a = *(const short8*)(&As[bsel][half][rowa * 64 + gr * 8]);
                }
                #pragma unroll
                for (int n = 0; n < 2; n++) {
                    const int rowb = n * 16 + lr;
                    const int gr = (ksl * 4 + lhi) ^ (rowb & 7);
                    b0[n] = *(const short8*)(&Bs0[bsel][half][rowb * 64 + gr * 8]);
                    b1[n] = *(const short8*)(&Bs1[bsel][half][rowb * 64 + gr * 8]);
                }
                #pragma unroll
                for (int n = 0; n < 2; n++) {
                    acc0[n] = __builtin_amdgcn_mfma_f32_16x16x32_bf16(a, b0[n], acc0[n], 0, 0, 0);
                    acc1[n] = __builtin_amdgcn_mfma_f32_16x16x32_bf16(a, b1[n], acc1[n], 0, 0, 0);
                }
            }
        }
        __builtin_amdgcn_s_setprio(0);
    };

    constexpr int NT = DDIM / 128;           // 16 (pow2)
    STAGEA(0, 0);
    PIN();
    LOADB_P(0);
    LOADB_Q(128);
    PIN();
    STOREB_P(0);
    sync_lgkm();
    for (int kt = 0; kt < NT; kt += 2) {
        // ---- phase A: tile kt from buf0 ----
        STAGEA(1, ((kt + 1) & (NT - 1)) * 128);
        PIN();
        LOADB_P(((kt + 2) & (NT - 1)) * 128);
        PIN();
        STOREB_Q(1);                          // B(kt+1) -> buf1
        asm volatile("s_waitcnt vmcnt(8)" ::: "memory");   // retires A(kt)+B(kt+1)
        PIN();
        COMPUTE(0);
        sync_lgkm();
        // ---- phase B: tile kt+1 from buf1 ----
        STAGEA(0, ((kt + 2) & (NT - 1)) * 128);
        PIN();
        LOADB_Q(((kt + 3) & (NT - 1)) * 128);
        PIN();
        STOREB_P(0);                          // B(kt+2) -> buf0
        asm volatile("s_waitcnt vmcnt(8)" ::: "memory");
        PIN();
        COMPUTE(1);
        sync_lgkm();
    }

    // epilogue: h = silu(g)*u.  C/D: col=lane&15, row=(lane>>4)*4+reg
    #pragma unroll
    for (int n = 0; n < 2; n++) {
        const int col = n0 + n * 16 + lr;
        #pragma unroll
        for (int j = 0; j < 4; j++) {
            const int row = r0g + wm + lhi * 4 + j;
            const float g = acc0[n][j], u = acc1[n][j];
            const float hv = g / (1.f + __expf(-g)) * u;
            h[(size_t)row * FDIM + col] = f2bf(hv);
        }
    }
}

// ---------------- down: eo = h @ D^T (bf16 out), BM=256, BN=64, BK=64 -------
// r16-proven kernel (best measured down). 1024 thr, LDS 80 KB.
__global__ __launch_bounds__(1024, 8) void down_kernel(
    const u16* __restrict__ h, const float* __restrict__ dp,
    u16* __restrict__ eo,
    const int* __restrict__ meta, const int* __restrict__ te256,
    const int* __restrict__ tr256)
{
    const int tile = blockIdx.y;
    const int nb = blockIdx.x;               // gridDim.x = DDIM/64 = 32
    if (tile >= meta[2]) return;
    const int n0 = nb * 64;
    const int e = te256[tile];
    const int r0g = tr256[tile];

    __shared__ __align__(16) u16 As[2][256 * 64];    // 32 KB / buf
    __shared__ __align__(16) u16 Bs[2][64 * 64];     //  8 KB / buf

    const int t = threadIdx.x;
    const int wid = t >> 6, lane = t & 63;
    const int lr = lane & 15, lhi = lane >> 4;
    const int wm = wid * 16;

    const u16* asrc[2];
    int aldsoff[2];
    #pragma unroll
    for (int j = 0; j < 2; j++) {
        const int row = wm + j * 8 + (lane >> 3);
        const int gran = (lane & 7) ^ (row & 7);
        asrc[j] = h + (size_t)(r0g + row) * FDIM + gran * 8;
        aldsoff[j] = (wid * 2 + j) * 512;
    }

    const int rb = t >> 4, c4 = t & 15;
    const float* brow = dp + (size_t)e * DDIM * FDIM + (size_t)(n0 + rb) * FDIM + c4 * 4;
    const int sOffB = rb * 64 + (((c4 >> 1) ^ (rb & 7)) * 8) + (c4 & 1) * 4;

    f32x4 acc[4];
    #pragma unroll
    for (int n = 0; n < 4; n++) acc[n] = f32x4{0.f,0.f,0.f,0.f};
    float4 pbP, pbQ;

    auto STAGEA = [&](int bsel, int k0) {
        #pragma unroll
        for (int j = 0; j < 2; j++)
            gload16(asrc[j] + k0, &As[bsel][aldsoff[j]]);
    };
    auto LOADB_P = [&](int k0) { pbP = *(const float4*)(brow + k0); };
    auto LOADB_Q = [&](int k0) { pbQ = *(const float4*)(brow + k0); };
    auto STOREB_P = [&](int bsel) {
        uint2 v; v.x = pack2(pbP.x, pbP.y); v.y = pack2(pbP.z, pbP.w);
        *(uint2*)(&Bs[bsel][sOffB]) = v;
    };
    auto STOREB_Q = [&](int bsel) {
        uint2 v; v.x = pack2(pbQ.x, pbQ.y); v.y = pack2(pbQ.z, pbQ.w);
        *(uint2*)(&Bs[bsel][sOffB]) = v;
    };
    auto COMPUTE = [&](int bsel) {
        __builtin_amdgcn_s_setprio(1);
        #pragma unroll
        for (int ks = 0; ks < 2; ks++) {
            short8 a;
            {
                const int rowa = wm + lr;
                const int gr = (ks * 4 + lhi) ^ (rowa & 7);
                a = *(const short8*)(&As[bsel][rowa * 64 + gr * 8]);
            }
            #pragma unroll
            for (int n = 0; n < 4; n++) {
                const int rowb = n * 16 + lr;
                const int gr = (ks * 4 + lhi) ^ (rowb & 7);
                const short8 b = *(const short8*)(&Bs[bsel][rowb * 64 + gr * 8]);
                acc[n] = __builtin_amdgcn_mfma_f32_16x16x32_bf16(a, b, acc[n], 0, 0, 0);
            }
        }
        __builtin_amdgcn_s_setprio(0);
    };

    constexpr int NT = FDIM / 64;            // 22 (even, not pow2)
    STAGEA(0, 0);
    PIN();
    LOADB_P(0);
    LOADB_Q(64);
    PIN();
    STOREB_P(0);
    sync_lgkm();
    for (int kt = 0; kt < NT; kt += 2) {
        int k1 = kt + 1; if (k1 >= NT) k1 = 0;
        int k2 = kt + 2; if (k2 >= NT) k2 = 0;
        int k3 = kt + 3; if (k3 >= NT) k3 = 0;
        // ---- phase A ----
        STAGEA(1, k1 * 64);
        PIN();
        LOADB_P(k2 * 64);
        PIN();
        STOREB_Q(1);
        asm volatile("s_waitcnt vmcnt(3)" ::: "memory");
        PIN();
        COMPUTE(0);
        sync_lgkm();
        // ---- phase B ----
        STAGEA(0, k2 * 64);
        PIN();
        LOADB_Q(k3 * 64);
        PIN();
        STOREB_P(0);
        asm volatile("s_waitcnt vmcnt(3)" ::: "memory");
        PIN();
        COMPUTE(1);
        sync_lgkm();
    }

    #pragma unroll
    for (int n = 0; n < 4; n++) {
        const int col = n0 + n * 16 + lr;
        #pragma unroll
        for (int j = 0; j < 4; j++) {
            const int row = r0g + wm + lhi * 4 + j;
            eo[(size_t)row * DDIM + col] = f2bf(acc[n][j]);
        }
    }
}

// ---------------- combine: out[t] = w1*eo[r1] + w2*eo[r2] (eo bf16) ---------
__global__ __launch_bounds__(256) void combine_kernel(
    const u16* __restrict__ eo, const int* __restrict__ tok_rows,
    const float* __restrict__ w, float* __restrict__ out)
{
    const int tok = blockIdx.x;
    const int r1 = tok_rows[tok * 2], r2 = tok_rows[tok * 2 + 1];
    const float w1 = w[tok * 2], w2 = w[tok * 2 + 1];
    const int d = threadIdx.x * 8;
    const uint4 a = *(const uint4*)(eo + (size_t)r1 * DDIM + d);
    const uint4 b = *(const uint4*)(eo + (size_t)r2 * DDIM + d);
    const u32 av[4] = {a.x, a.y, a.z, a.w};
    const u32 bv[4] = {b.x, b.y, b.z, b.w};
    float4 o0, o1;
    float* op[8] = {&o0.x, &o0.y, &o0.z, &o0.w, &o1.x, &o1.y, &o1.z, &o1.w};
    #pragma unroll
    for (int i = 0; i < 4; i++) {
        *op[2 * i]     = w1 * bf2f((u16)(av[i] & 0xffff)) + w2 * bf2f((u16)(bv[i] & 0xffff));
        *op[2 * i + 1] = w1 * bf2f((u16)(av[i] >> 16))    + w2 * bf2f((u16)(bv[i] >> 16));
    }
    float4* po = (float4*)(out + (size_t)tok * DDIM + d);
    po[0] = o0; po[1] = o1;
}

extern "C" void kernel_launch(void* const* d_in, const int* in_sizes, int n_in,
                              void* d_out, int out_size, void* d_ws, size_t ws_size,
                              hipStream_t stream) {
    const float* x  = (const float*)d_in[0];
    const float* gw = (const float*)d_in[1];
    const float* gp = (const float*)d_in[2];
    const float* up = (const float*)d_in[3];
    const float* dp = (const float*)d_in[4];
    float* out = (float*)d_out;
    char* ws = (char*)d_ws;

    int*   meta     = (int*)(ws + O_META);
    int*   te128    = (int*)(ws + O_TE128);
    int*   tr128    = (int*)(ws + O_TR128);
    int*   te256    = (int*)(ws + O_TE256);
    int*   tr256    = (int*)(ws + O_TR256);
    int*   row_tok  = (int*)(ws + O_ROWTOK);
    int*   tok_rows = (int*)(ws + O_TOKROWS);
    int*   sel      = (int*)(ws + O_SEL);
    float* w        = (float*)(ws + O_W);
    u16*   xbf      = (u16*)(ws + O_XBF);
    u16*   h        = (u16*)(ws + O_H);
    u16*   eo       = (u16*)(ws + O_EO);

    router_kernel<<<N_TOK, 256, 0, stream>>>(x, gw, sel, w, xbf);
    build_kernel<<<1, 512, 0, stream>>>(sel, meta, te128, tr128, te256, tr256,
                                        row_tok, tok_rows);
    mlp1_kernel<<<dim3(FDIM / 32, NT128), 512, 0, stream>>>(
        xbf, gp, up, h, meta, te128, tr128, row_tok);
    down_kernel<<<dim3(DDIM / 64, NT256), 1024, 0, stream>>>(
        h, dp, eo, meta, te256, tr256);
    combine_kernel<<<N_TOK, 256, 0, stream>>>(eo, tok_rows, w, out);
}

// Round 19
// 173.300 us; speedup vs baseline: 1.2914x; 1.2914x over previous
//
#include <hip/hip_runtime.h>
#include <hip/hip_bf16.h>
#include <stdint.h>

typedef __attribute__((ext_vector_type(8))) short short8;
typedef __attribute__((ext_vector_type(4))) float f32x4;
typedef unsigned int u32;
typedef unsigned short u16;

static constexpr int N_TOK = 1024;
static constexpr int DDIM = 2048;
static constexpr int FDIM = 1408;
static constexpr int NEXP = 8;
static constexpr int MAXROWS = 4096;    // 2048 + 8*255 < 4096 (256-row padding)
static constexpr int NT256 = 16;        // max 256-row tiles

// ---- workspace byte offsets ----
static constexpr size_t O_META   = 0;                                  // 64 ints
static constexpr size_t O_TE     = 256;                                // 16 ints
static constexpr size_t O_TR     = 384;                                // 16 ints
static constexpr size_t O_ROWTOK = 768;                                // MAXROWS ints
static constexpr size_t O_TOKROWS= O_ROWTOK + (size_t)MAXROWS * 4;     // 2048 ints
static constexpr size_t O_SEL    = O_TOKROWS + 2048 * 4;               // 2048 ints
static constexpr size_t O_W      = O_SEL + 2048 * 4;                   // 2048 floats
static constexpr size_t O_XBF    = (O_W + 2048 * 4 + 255) & ~(size_t)255; // (N_TOK+1)*DDIM bf16
static constexpr size_t O_H      = O_XBF + (size_t)(N_TOK + 1) * DDIM * 2; // MAXROWS*FDIM bf16
static constexpr size_t O_EO     = O_H + (size_t)MAXROWS * FDIM * 2;   // MAXROWS*DDIM bf16

static __device__ __forceinline__ u16 f2bf(float f) {
    return __builtin_bit_cast(u16, __float2bfloat16(f));   // RNE via v_cvt
}
static __device__ __forceinline__ float bf2f(u16 s) {
    u32 u = ((u32)s) << 16;
    return __builtin_bit_cast(float, u);
}
static __device__ __forceinline__ u32 pack2(float a, float b) {
    return (u32)f2bf(a) | ((u32)f2bf(b) << 16);
}
// async global->LDS DMA, 16B/lane. LDS base wave-uniform; HW adds lane*16.
static __device__ __forceinline__ void gload16(const void* g, void* l) {
    __builtin_amdgcn_global_load_lds(
        (const __attribute__((address_space(1))) void*)g,
        (__attribute__((address_space(3))) void*)l, 16, 0, 0);
}
#define PIN() __builtin_amdgcn_sched_barrier(0)
// publish LDS writes + raw barrier (no vmcnt drain — loads stay in flight)
static __device__ __forceinline__ void sync_lgkm() {
    asm volatile("s_waitcnt lgkmcnt(0)" ::: "memory");
    __builtin_amdgcn_s_barrier();
    __builtin_amdgcn_sched_barrier(0);
}

// ------- router (+fused xcast): logits, top-2, softmax; writes xbf ---------
__global__ __launch_bounds__(256) void router_kernel(
    const float* __restrict__ x, const float* __restrict__ gw,
    int* __restrict__ sel, float* __restrict__ wout, u16* __restrict__ xbf)
{
    __shared__ float xs[DDIM];
    __shared__ float lg[NEXP];
    const int tok = blockIdx.x;
    const float* xr = x + (size_t)tok * DDIM;
    for (int i = threadIdx.x; i < DDIM / 4; i += 256)
        ((float4*)xs)[i] = ((const float4*)xr)[i];
    __syncthreads();
    {
        const int i = threadIdx.x * 8;
        uint4 v;
        v.x = pack2(xs[i], xs[i + 1]);     v.y = pack2(xs[i + 2], xs[i + 3]);
        v.z = pack2(xs[i + 4], xs[i + 5]); v.w = pack2(xs[i + 6], xs[i + 7]);
        *(uint4*)(xbf + (size_t)tok * DDIM + i) = v;
        if (tok == 0)                      // zero pad row (gathers of tok==-1)
            *(uint4*)(xbf + (size_t)N_TOK * DDIM + i) = uint4{0u, 0u, 0u, 0u};
    }
    const int wid = threadIdx.x >> 6, lane = threadIdx.x & 63;
    for (int i = 0; i < 2; i++) {
        const int e = wid * 2 + i;
        const float* g = gw + (size_t)e * DDIM;
        float s = 0.f;
        for (int k = lane; k < DDIM; k += 64) s += xs[k] * g[k];
        for (int off = 32; off > 0; off >>= 1) s += __shfl_down(s, off);
        if (lane == 0) lg[e] = s;
    }
    __syncthreads();
    if (threadIdx.x == 0) {
        int i1 = 0;
        for (int e = 1; e < NEXP; e++) if (lg[e] > lg[i1]) i1 = e;
        int i2 = -1;
        for (int e = 0; e < NEXP; e++) {
            if (e == i1) continue;
            if (i2 < 0 || lg[e] > lg[i2]) i2 = e;
        }
        const float e2 = __expf(lg[i2] - lg[i1]);
        const float w1 = 1.f / (1.f + e2);
        sel[tok * 2] = i1; sel[tok * 2 + 1] = i2;
        wout[tok * 2] = w1; wout[tok * 2 + 1] = e2 * w1;
    }
}

// -------- deterministic routing build (1 block, 8 waves); 256-row padding ----
__global__ __launch_bounds__(512) void build_kernel(
    const int* __restrict__ sel,
    int* __restrict__ meta, int* __restrict__ te, int* __restrict__ tr,
    int* __restrict__ row_tok, int* __restrict__ tok_rows)
{
    __shared__ int s0[N_TOK], s1[N_TOK];
    __shared__ u16 p0[N_TOK], p1[N_TOK];
    __shared__ int counts[NEXP], offs[NEXP];
    for (int i = threadIdx.x; i < N_TOK; i += 512) {
        s0[i] = sel[i * 2]; s1[i] = sel[i * 2 + 1];
    }
    __syncthreads();
    const int e = threadIdx.x >> 6, lane = threadIdx.x & 63;
    int base = 0;
    for (int c = 0; c < N_TOK / 64; c++) {
        const int tk = c * 64 + lane;
        const int slot = (s0[tk] == e) ? 0 : ((s1[tk] == e) ? 1 : -1);
        const unsigned long long m = __ballot(slot >= 0);
        const int pre = __popcll(m & ((1ull << lane) - 1ull));
        if (slot == 0) p0[tk] = (u16)(base + pre);
        else if (slot == 1) p1[tk] = (u16)(base + pre);
        base += __popcll(m);
    }
    if (lane == 0) counts[e] = base;
    __syncthreads();
    if (threadIdx.x == 0) {
        int off = 0, nt = 0;
        for (int qq = 0; qq < NEXP; qq++) {
            offs[qq] = off;
            const int pc = (counts[qq] + 255) & ~255;
            for (int i = 0; i < pc / 256; i++) { te[nt] = qq; tr[nt] = off + i * 256; nt++; }
            off += pc;
        }
        meta[0] = nt; meta[1] = off;
    }
    __syncthreads();
    const int off = offs[e];
    for (int c = 0; c < N_TOK / 64; c++) {
        const int tk = c * 64 + lane;
        const int slot = (s0[tk] == e) ? 0 : ((s1[tk] == e) ? 1 : -1);
        if (slot >= 0) {
            const int row = off + (slot ? p1[tk] : p0[tk]);
            row_tok[row] = tk;
            tok_rows[tk * 2 + slot] = row;
        }
    }
    const int cnt = counts[e];
    const int pc = (cnt + 255) & ~255;
    for (int p = cnt + lane; p < pc; p += 64) row_tok[off + p] = -1;
}

// ------- mlp1: h = silu(x@G^T)*(x@U^T), BM=256, BN=32/mat, BK=64 ------------
// 1024 thr = 16 wave-private waves. Counted-vmcnt schedule. LDS 80KB -> 2/CU.
__global__ __launch_bounds__(1024, 8) void mlp1_kernel(
    const u16* __restrict__ xbf,
    const float* __restrict__ gp, const float* __restrict__ upw,
    u16* __restrict__ h,
    const int* __restrict__ meta, const int* __restrict__ te,
    const int* __restrict__ tr, const int* __restrict__ row_tok)
{
    const int tile = blockIdx.y;
    const int nb = blockIdx.x;               // gridDim.x = FDIM/32 = 44
    if (tile >= meta[0]) return;
    const int n0 = nb * 32;
    const int e = te[tile];
    const int r0g = tr[tile];

    __shared__ __align__(16) u16 As[2][256 * 64];    // 32 KB / buf
    __shared__ __align__(16) u16 Bs[2][2][32 * 64];  // [mat][buf], 4 KB each

    const int t = threadIdx.x;
    const int wid = t >> 6, lane = t & 63;           // wid 0..15
    const int lr = lane & 15, lhi = lane >> 4;
    const int wm = wid * 16;                         // wave-private 16 rows

    // --- A staging (gload_lds): wave w stages rows w*16..w*16+16 ---
    const u16* asrc[2];
    int aldsoff[2];                          // u16 units, wave-uniform
    #pragma unroll
    for (int j = 0; j < 2; j++) {
        const int row = wm + j * 8 + (lane >> 3);
        const int gran = (lane & 7) ^ (row & 7);     // pre-swizzled source granule
        const int tok = row_tok[r0g + row];
        asrc[j] = xbf + (size_t)(tok < 0 ? N_TOK : tok) * DDIM + gran * 8;
        aldsoff[j] = (wid * 2 + j) * 512;            // linear dest, 16B/lane
    }

    // --- B staging (reg, cvt-on-write): threads 0-511 gate, 512-1023 up ---
    const int mat = t >> 9, tl = t & 511;
    const int rb = tl >> 4, c4 = tl & 15;    // row 0..31, float4-col 0..15
    const float* brow = (mat ? upw : gp)
        + (size_t)e * FDIM * DDIM + (size_t)(n0 + rb) * DDIM + c4 * 4;
    u16* bst = &Bs[mat][0][0];
    const int sOffB = rb * 64 + (((c4 >> 1) ^ (rb & 7)) * 8) + (c4 & 1) * 4;

    f32x4 acc0[2], acc1[2];
    acc0[0] = acc0[1] = acc1[0] = acc1[1] = f32x4{0.f, 0.f, 0.f, 0.f};
    float4 pbP, pbQ;                          // B regs, sets P/Q (1 float4 each)

    auto STAGEA = [&](int bsel, int k0) {
        #pragma unroll
        for (int j = 0; j < 2; j++)
            gload16(asrc[j] + k0, &As[bsel][aldsoff[j]]);
    };
    auto LOADB_P = [&](int k0) { pbP = *(const float4*)(brow + k0); };
    auto LOADB_Q = [&](int k0) { pbQ = *(const float4*)(brow + k0); };
    auto STOREB_P = [&](int bsel) {
        uint2 v; v.x = pack2(pbP.x, pbP.y); v.y = pack2(pbP.z, pbP.w);
        *(uint2*)(bst + bsel * 2048 + sOffB) = v;
    };
    auto STOREB_Q = [&](int bsel) {
        uint2 v; v.x = pack2(pbQ.x, pbQ.y); v.y = pack2(pbQ.z, pbQ.w);
        *(uint2*)(bst + bsel * 2048 + sOffB) = v;
    };
    auto COMPUTE = [&](int bsel) {
        __builtin_amdgcn_s_setprio(1);
        #pragma unroll
        for (int ks = 0; ks < 2; ks++) {
            short8 a, b0[2], b1[2];
            {
                const int rowa = wm + lr;
                const int gr = (ks * 4 + lhi) ^ (rowa & 7);
                a = *(const short8*)(&As[bsel][rowa * 64 + gr * 8]);
            }
            #pragma unroll
            for (int n = 0; n < 2; n++) {
                const int rowb = n * 16 + lr;
                const int gr = (ks * 4 + lhi) ^ (rowb & 7);
                b0[n] = *(const short8*)(&Bs[0][bsel][rowb * 64 + gr * 8]);
                b1[n] = *(const short8*)(&Bs[1][bsel][rowb * 64 + gr * 8]);
            }
            #pragma unroll
            for (int n = 0; n < 2; n++) {
                acc0[n] = __builtin_amdgcn_mfma_f32_16x16x32_bf16(a, b0[n], acc0[n], 0, 0, 0);
                acc1[n] = __builtin_amdgcn_mfma_f32_16x16x32_bf16(a, b1[n], acc1[n], 0, 0, 0);
            }
        }
        __builtin_amdgcn_s_setprio(0);
    };

    constexpr int NT = DDIM / 64;            // 32 (pow2)
    STAGEA(0, 0);
    PIN();
    LOADB_P(0);
    LOADB_Q(64);
    PIN();
    STOREB_P(0);
    sync_lgkm();
    for (int kt = 0; kt < NT; kt += 2) {
        // ---- phase A: tile kt from buf0 ----
        STAGEA(1, ((kt + 1) & (NT - 1)) * 64);
        PIN();
        LOADB_P(((kt + 2) & (NT - 1)) * 64);
        PIN();
        STOREB_Q(1);                          // B(kt+1) -> buf1
        asm volatile("s_waitcnt vmcnt(3)" ::: "memory");   // retires A(kt)+B(kt+1)
        PIN();
        COMPUTE(0);
        sync_lgkm();
        // ---- phase B: tile kt+1 from buf1 ----
        STAGEA(0, ((kt + 2) & (NT - 1)) * 64);
        PIN();
        LOADB_Q(((kt + 3) & (NT - 1)) * 64);
        PIN();
        STOREB_P(0);                          // B(kt+2) -> buf0
        asm volatile("s_waitcnt vmcnt(3)" ::: "memory");
        PIN();
        COMPUTE(1);
        sync_lgkm();
    }

    // epilogue: h = silu(g)*u.  C/D: col=lane&15, row=(lane>>4)*4+reg
    #pragma unroll
    for (int n = 0; n < 2; n++) {
        const int col = n0 + n * 16 + lr;
        #pragma unroll
        for (int j = 0; j < 4; j++) {
            const int row = r0g + wm + lhi * 4 + j;
            const float g = acc0[n][j], u = acc1[n][j];
            const float hv = g / (1.f + __expf(-g)) * u;
            h[(size_t)row * FDIM + col] = f2bf(hv);
        }
    }
}

// ---------------- down: eo = h @ D^T (bf16 out), BM=256, BN=64, BK=64 -------
// 1024 thr, 16 wave-private waves; vmcnt(3); LDS 80KB -> 2/CU.
__global__ __launch_bounds__(1024, 8) void down_kernel(
    const u16* __restrict__ h, const float* __restrict__ dp,
    u16* __restrict__ eo,
    const int* __restrict__ meta, const int* __restrict__ te,
    const int* __restrict__ tr)
{
    const int tile = blockIdx.y;
    const int nb = blockIdx.x;               // gridDim.x = DDIM/64 = 32
    if (tile >= meta[0]) return;
    const int n0 = nb * 64;
    const int e = te[tile];
    const int r0g = tr[tile];

    __shared__ __align__(16) u16 As[2][256 * 64];    // 32 KB / buf
    __shared__ __align__(16) u16 Bs[2][64 * 64];     //  8 KB / buf

    const int t = threadIdx.x;
    const int wid = t >> 6, lane = t & 63;
    const int lr = lane & 15, lhi = lane >> 4;
    const int wm = wid * 16;

    // --- A staging (gload_lds): wave-private rows w*16..w*16+16 ---
    const u16* asrc[2];
    int aldsoff[2];
    #pragma unroll
    for (int j = 0; j < 2; j++) {
        const int row = wm + j * 8 + (lane >> 3);
        const int gran = (lane & 7) ^ (row & 7);
        asrc[j] = h + (size_t)(r0g + row) * FDIM + gran * 8;
        aldsoff[j] = (wid * 2 + j) * 512;
    }

    // --- B staging (reg, cvt-on-write): row rb (0..63), float4-col c4 ---
    const int rb = t >> 4, c4 = t & 15;
    const float* brow = dp + (size_t)e * DDIM * FDIM + (size_t)(n0 + rb) * FDIM + c4 * 4;
    const int sOffB = rb * 64 + (((c4 >> 1) ^ (rb & 7)) * 8) + (c4 & 1) * 4;

    f32x4 acc[4];
    #pragma unroll
    for (int n = 0; n < 4; n++) acc[n] = f32x4{0.f,0.f,0.f,0.f};
    float4 pbP, pbQ;

    auto STAGEA = [&](int bsel, int k0) {
        #pragma unroll
        for (int j = 0; j < 2; j++)
            gload16(asrc[j] + k0, &As[bsel][aldsoff[j]]);
    };
    auto LOADB_P = [&](int k0) { pbP = *(const float4*)(brow + k0); };
    auto LOADB_Q = [&](int k0) { pbQ = *(const float4*)(brow + k0); };
    auto STOREB_P = [&](int bsel) {
        uint2 v; v.x = pack2(pbP.x, pbP.y); v.y = pack2(pbP.z, pbP.w);
        *(uint2*)(&Bs[bsel][sOffB]) = v;
    };
    auto STOREB_Q = [&](int bsel) {
        uint2 v; v.x = pack2(pbQ.x, pbQ.y); v.y = pack2(pbQ.z, pbQ.w);
        *(uint2*)(&Bs[bsel][sOffB]) = v;
    };
    auto COMPUTE = [&](int bsel) {
        __builtin_amdgcn_s_setprio(1);
        #pragma unroll
        for (int ks = 0; ks < 2; ks++) {
            short8 a;
            {
                const int rowa = wm + lr;
                const int gr = (ks * 4 + lhi) ^ (rowa & 7);
                a = *(const short8*)(&As[bsel][rowa * 64 + gr * 8]);
            }
            #pragma unroll
            for (int n = 0; n < 4; n++) {
                const int rowb = n * 16 + lr;
                const int gr = (ks * 4 + lhi) ^ (rowb & 7);
                const short8 b = *(const short8*)(&Bs[bsel][rowb * 64 + gr * 8]);
                acc[n] = __builtin_amdgcn_mfma_f32_16x16x32_bf16(a, b, acc[n], 0, 0, 0);
            }
        }
        __builtin_amdgcn_s_setprio(0);
    };

    constexpr int NT = FDIM / 64;            // 22 (even, not pow2)
    STAGEA(0, 0);
    PIN();
    LOADB_P(0);
    LOADB_Q(64);
    PIN();
    STOREB_P(0);
    sync_lgkm();
    for (int kt = 0; kt < NT; kt += 2) {
        int k1 = kt + 1; if (k1 >= NT) k1 = 0;
        int k2 = kt + 2; if (k2 >= NT) k2 = 0;
        int k3 = kt + 3; if (k3 >= NT) k3 = 0;
        // ---- phase A ----
        STAGEA(1, k1 * 64);
        PIN();
        LOADB_P(k2 * 64);
        PIN();
        STOREB_Q(1);
        asm volatile("s_waitcnt vmcnt(3)" ::: "memory");
        PIN();
        COMPUTE(0);
        sync_lgkm();
        // ---- phase B ----
        STAGEA(0, k2 * 64);
        PIN();
        LOADB_Q(k3 * 64);
        PIN();
        STOREB_P(0);
        asm volatile("s_waitcnt vmcnt(3)" ::: "memory");
        PIN();
        COMPUTE(1);
        sync_lgkm();
    }

    #pragma unroll
    for (int n = 0; n < 4; n++) {
        const int col = n0 + n * 16 + lr;
        #pragma unroll
        for (int j = 0; j < 4; j++) {
            const int row = r0g + wm + lhi * 4 + j;
            eo[(size_t)row * DDIM + col] = f2bf(acc[n][j]);
        }
    }
}

// ---------------- combine: out[t] = w1*eo[r1] + w2*eo[r2] (eo bf16) ---------
__global__ __launch_bounds__(256) void combine_kernel(
    const u16* __restrict__ eo, const int* __restrict__ tok_rows,
    const float* __restrict__ w, float* __restrict__ out)
{
    const int tok = blockIdx.x;
    const int r1 = tok_rows[tok * 2], r2 = tok_rows[tok * 2 + 1];
    const float w1 = w[tok * 2], w2 = w[tok * 2 + 1];
    const int d = threadIdx.x * 8;
    const uint4 a = *(const uint4*)(eo + (size_t)r1 * DDIM + d);
    const uint4 b = *(const uint4*)(eo + (size_t)r2 * DDIM + d);
    const u32 av[4] = {a.x, a.y, a.z, a.w};
    const u32 bv[4] = {b.x, b.y, b.z, b.w};
    float4 o0, o1;
    float* op[8] = {&o0.x, &o0.y, &o0.z, &o0.w, &o1.x, &o1.y, &o1.z, &o1.w};
    #pragma unroll
    for (int i = 0; i < 4; i++) {
        *op[2 * i]     = w1 * bf2f((u16)(av[i] & 0xffff)) + w2 * bf2f((u16)(bv[i] & 0xffff));
        *op[2 * i + 1] = w1 * bf2f((u16)(av[i] >> 16))    + w2 * bf2f((u16)(bv[i] >> 16));
    }
    float4* po = (float4*)(out + (size_t)tok * DDIM + d);
    po[0] = o0; po[1] = o1;
}

extern "C" void kernel_launch(void* const* d_in, const int* in_sizes, int n_in,
                              void* d_out, int out_size, void* d_ws, size_t ws_size,
                              hipStream_t stream) {
    const float* x  = (const float*)d_in[0];
    const float* gw = (const float*)d_in[1];
    const float* gp = (const float*)d_in[2];
    const float* up = (const float*)d_in[3];
    const float* dp = (const float*)d_in[4];
    float* out = (float*)d_out;
    char* ws = (char*)d_ws;

    int*   meta     = (int*)(ws + O_META);
    int*   te       = (int*)(ws + O_TE);
    int*   tr       = (int*)(ws + O_TR);
    int*   row_tok  = (int*)(ws + O_ROWTOK);
    int*   tok_rows = (int*)(ws + O_TOKROWS);
    int*   sel      = (int*)(ws + O_SEL);
    float* w        = (float*)(ws + O_W);
    u16*   xbf      = (u16*)(ws + O_XBF);
    u16*   h        = (u16*)(ws + O_H);
    u16*   eo       = (u16*)(ws + O_EO);

    router_kernel<<<N_TOK, 256, 0, stream>>>(x, gw, sel, w, xbf);
    build_kernel<<<1, 512, 0, stream>>>(sel, meta, te, tr, row_tok, tok_rows);
    mlp1_kernel<<<dim3(FDIM / 32, NT256), 1024, 0, stream>>>(
        xbf, gp, up, h, meta, te, tr, row_tok);
    down_kernel<<<dim3(DDIM / 64, NT256), 1024, 0, stream>>>(
        h, dp, eo, meta, te, tr);
    combine_kernel<<<N_TOK, 256, 0, stream>>>(eo, tok_rows, w, out);
}